// Round 4
// baseline (1338.800 us; speedup 1.0000x reference)
//
#include <hip/hip_runtime.h>
#include <hip/hip_bf16.h>
#include <stdint.h>

// INT4Linear: out[m,o] = sum_k x[m,k]*W[o,k]*scale + bias[o]
// M=8192, N=4096, K=4096. x/scale/bias/out fp32 on device; weight int32
// (one sign-extended packed byte). Pipeline:
//   convert_x (fp32->bf16), dequant_w (int4->bf16), gemm8p (256x256x64).
// Round-4 gemm8p: LDS->reg reads software-pipelined ONE PHASE AHEAD of their
// MFMA use; compiler inserts counted lgkmcnt before consumers; one structural
// lgkmcnt(0)+vmcnt(0)+barrier per K-tile (P3-end) + one pacing barrier (P4-end).

typedef __bf16 bf16;
typedef __bf16 bf16x8 __attribute__((ext_vector_type(8)));
typedef float  f32x4  __attribute__((ext_vector_type(4)));

constexpr int M_DIM = 8192;
constexpr int N_DIM = 4096;
constexpr int K_DIM = 4096;
constexpr int KB    = K_DIM / 2;

constexpr int BM = 256;
constexpr int BN = 256;
constexpr int BK = 64;
constexpr int NKT = K_DIM / BK;   // 64 K-tiles

__device__ __forceinline__ void gload_lds16(const void* g, void* l) {
  __builtin_amdgcn_global_load_lds(
      (const __attribute__((address_space(1))) void*)g,
      (__attribute__((address_space(3))) void*)l,
      16, 0, 0);
}

__device__ __forceinline__ void fence_barrier() {
  asm volatile("" ::: "memory");
  __builtin_amdgcn_s_barrier();
  asm volatile("" ::: "memory");
}

__device__ __forceinline__ float dq_hi_f(int b) {
  int sb = (int)(signed char)(b & 0xFF);
  return (float)(sb >> 4);
}
__device__ __forceinline__ float dq_lo_f(int b) {
  int sb = (int)(signed char)(b & 0xFF);
  return (float)(((sb & 15) ^ 8) - 8);
}

// ---------------- x: fp32 -> bf16 ----------------
__global__ void convert_x(const float* __restrict__ x, bf16* __restrict__ xc) {
  const size_t i = (size_t)blockIdx.x * 256 + threadIdx.x;
  const float4 a = ((const float4*)x)[2 * i];
  const float4 b = ((const float4*)x)[2 * i + 1];
  bf16x8 o;
  o[0] = (bf16)a.x; o[1] = (bf16)a.y; o[2] = (bf16)a.z; o[3] = (bf16)a.w;
  o[4] = (bf16)b.x; o[5] = (bf16)b.y; o[6] = (bf16)b.z; o[7] = (bf16)b.w;
  *(bf16x8*)(xc + i * 8) = o;
}

// ---------------- W: packed int4 -> bf16 [N][K] ----------------
__global__ void dequant_w(const int* __restrict__ wq, bf16* __restrict__ W,
                          const float* __restrict__ scale_p) {
  const float s = scale_p[0];
  const size_t idx = (size_t)blockIdx.x * 256 + threadIdx.x;
  const int4 v = ((const int4*)wq)[idx];
  bf16x8 o;
  o[0] = (bf16)(dq_hi_f(v.x) * s); o[1] = (bf16)(dq_lo_f(v.x) * s);
  o[2] = (bf16)(dq_hi_f(v.y) * s); o[3] = (bf16)(dq_lo_f(v.y) * s);
  o[4] = (bf16)(dq_hi_f(v.z) * s); o[5] = (bf16)(dq_lo_f(v.z) * s);
  o[6] = (bf16)(dq_hi_f(v.w) * s); o[7] = (bf16)(dq_lo_f(v.w) * s);
  *(bf16x8*)(W + idx * 8) = o;
}

// ---------------- pipelined 256x256 GEMM ----------------
// 512 threads = 8 waves (2M x 4N), per-wave output 128x64.
// LDS: dbuf A[256][64] + B[256][64] bf16 = 128 KiB. Swizzle: col ^= (row&7)<<3
// (write via pre-swizzled global source, read via XOR on col).
// Per K-tile kt (buf=kt&1):
//  P1: stage B(kt+1) | read a1,b1 (ksub1, buf) | MFMA a0c x b0c -> acc[0..3]
//  P2:                                          MFMA a0c+4 x b0c -> acc[4..7]
//  P3:                                          MFMA a1 x b1 -> acc[0..3]
//      lgkmcnt(0); vmcnt(0); barrier   <- all reads of buf done; all staging landed
//  P4: stage A(kt+2) [into buf, legal after P3 bar] | read a0n,b0n (ksub0, buf^1)
//      MFMA a1+4 x b1 -> acc[4..7]; barrier
// Reads issued in P1 feed P3/P4; reads in P4 feed next tile's P1/P2 -> LDS
// service overlaps MFMA issue; compiler emits counted lgkmcnt for consumers.

#define MMA16(AF, BF, ACCOFF)                                                  \
  {                                                                            \
    _Pragma("unroll") for (int i_ = 0; i_ < 4; ++i_) {                         \
      _Pragma("unroll") for (int j_ = 0; j_ < 4; ++j_) {                       \
        acc[(ACCOFF) + i_][j_] = __builtin_amdgcn_mfma_f32_16x16x32_bf16(      \
            (AF)[i_], (BF)[j_], acc[(ACCOFF) + i_][j_], 0, 0, 0);              \
      }                                                                        \
    }                                                                          \
  }

__global__ void __launch_bounds__(512, 2)
gemm8p(const bf16* __restrict__ Xc, const bf16* __restrict__ W,
       const float* __restrict__ bias, float* __restrict__ out) {
  __shared__ __align__(16) bf16 As[2][BM][BK];
  __shared__ __align__(16) bf16 Bs[2][BN][BK];

  const int tid = threadIdx.x;
  const int w   = tid >> 6;       // wave 0..7
  const int l   = tid & 63;
  const int wm  = w >> 2;         // M half
  const int wn  = w & 3;          // N quarter
  const int lrow = l & 15, lg = l >> 4;

  // bijective XCD swizzle: 512 wgs, 512%8==0
  const int bid = blockIdx.x;
  const int wg  = (bid & 7) * 64 + (bid >> 3);
  const int m0  = (wg >> 4) * BM;
  const int n0  = (wg & 15) * BN;

  // staging lane geometry (pre-swizzled source)
  const int srow = l >> 3;
  const int scol = ((l & 7) ^ srow) << 3;
  const bf16* gA = Xc + (size_t)(m0 + w * 16 + srow) * K_DIM + scol;
  const bf16* gB = W  + (size_t)(n0 + w * 16 + srow) * K_DIM + scol;

  const int rsw = (lrow & 7) << 3;   // read-side col XOR (elements)

  f32x4 acc[8][4] = {};

#define STAGE_A(KT, H)                                                         \
  {                                                                            \
    gload_lds16(gA + (size_t)((H) * 128) * K_DIM + (KT) * BK,                  \
                &As[(KT) & 1][(H) * 128 + w * 16][0]);                         \
    gload_lds16(gA + (size_t)((H) * 128 + 8) * K_DIM + (KT) * BK,              \
                &As[(KT) & 1][(H) * 128 + w * 16 + 8][0]);                     \
  }
#define STAGE_B(KT, H)                                                         \
  {                                                                            \
    gload_lds16(gB + (size_t)((H) * 128) * K_DIM + (KT) * BK,                  \
                &Bs[(KT) & 1][(H) * 128 + w * 16][0]);                         \
    gload_lds16(gB + (size_t)((H) * 128 + 8) * K_DIM + (KT) * BK,              \
                &Bs[(KT) & 1][(H) * 128 + w * 16 + 8][0]);                     \
  }

#define READ_KS0(BUF, AD, BD)                                                  \
  {                                                                            \
    _Pragma("unroll") for (int i_ = 0; i_ < 8; ++i_)                           \
      AD[i_] = *(const bf16x8*)&As[BUF][wm * 128 + i_ * 16 + lrow][(lg * 8) ^ rsw]; \
    _Pragma("unroll") for (int j_ = 0; j_ < 4; ++j_)                           \
      BD[j_] = *(const bf16x8*)&Bs[BUF][wn * 64 + j_ * 16 + lrow][(lg * 8) ^ rsw];  \
  }
#define READ_KS1(BUF, AD, BD)                                                  \
  {                                                                            \
    _Pragma("unroll") for (int i_ = 0; i_ < 8; ++i_)                           \
      AD[i_] = *(const bf16x8*)&As[BUF][wm * 128 + i_ * 16 + lrow][(32 + lg * 8) ^ rsw]; \
    _Pragma("unroll") for (int j_ = 0; j_ < 4; ++j_)                           \
      BD[j_] = *(const bf16x8*)&Bs[BUF][wn * 64 + j_ * 16 + lrow][(32 + lg * 8) ^ rsw]; \
  }

  bf16x8 a0A[8], a0B[8], a1[8];
  bf16x8 b0A[4], b0B[4], b1[4];

  // ---- prologue ----
  STAGE_A(0, 0); STAGE_A(0, 1); STAGE_B(0, 0); STAGE_B(0, 1);   // buf0: 8 loads
  STAGE_A(1, 0); STAGE_A(1, 1);                                 // buf1: 4 loads
  asm volatile("s_waitcnt vmcnt(4)" ::: "memory");              // K-tile 0 landed
  fence_barrier();
  READ_KS0(0, a0A, b0A);                                        // feeds kt=0 P1/P2

#define TILE(KT, BUF, A0C, B0C, A0N, B0N)                                      \
  {                                                                            \
    /* P1 */                                                                   \
    if ((KT) + 1 < NKT) { STAGE_B((KT) + 1, 0); STAGE_B((KT) + 1, 1); }        \
    READ_KS1(BUF, a1, b1);                                                     \
    __builtin_amdgcn_s_setprio(1);                                             \
    MMA16(A0C, B0C, 0);                                                        \
    /* P2 */                                                                   \
    MMA16(A0C + 4, B0C, 4);                                                    \
    /* P3 */                                                                   \
    MMA16(a1, b1, 0);                                                          \
    __builtin_amdgcn_s_setprio(0);                                             \
    asm volatile("s_waitcnt lgkmcnt(0)" ::: "memory");                         \
    asm volatile("s_waitcnt vmcnt(0)" ::: "memory");                           \
    fence_barrier();                                                           \
    /* P4 */                                                                   \
    if ((KT) + 2 < NKT) { STAGE_A((KT) + 2, 0); STAGE_A((KT) + 2, 1); }        \
    if ((KT) + 1 < NKT) { READ_KS0((BUF) ^ 1, A0N, B0N); }                     \
    __builtin_amdgcn_s_setprio(1);                                             \
    MMA16(a1 + 4, b1, 4);                                                      \
    __builtin_amdgcn_s_setprio(0);                                             \
    fence_barrier();                                                           \
  }

  for (int kt = 0; kt < NKT; kt += 2) {
    TILE(kt,     0, a0A, b0A, a0B, b0B);
    TILE(kt + 1, 1, a0B, b0B, a0A, b0A);
  }

  // ---- epilogue: +bias, fp32 store ----
  float bv[4];
#pragma unroll
  for (int j = 0; j < 4; ++j) bv[j] = bias[n0 + wn * 64 + j * 16 + lrow];

#pragma unroll
  for (int i = 0; i < 8; ++i) {
#pragma unroll
    for (int r = 0; r < 4; ++r) {
      float* orow = out + (size_t)(m0 + wm * 128 + i * 16 + lg * 4 + r) * N_DIM
                        + (n0 + wn * 64 + lrow);
#pragma unroll
      for (int j = 0; j < 4; ++j) orow[j * 16] = acc[i][j][r] + bv[j];
    }
  }
}

// ---------------- fallback (ws too small): fused simple GEMM ----------------
__global__ void __launch_bounds__(256)
gemm_fused(const float* __restrict__ Xf, const int* __restrict__ WQ,
           const float* __restrict__ scale_p, const float* __restrict__ bias,
           float* __restrict__ out) {
  __shared__ __align__(16) bf16 As[128][64];
  __shared__ __align__(16) bf16 Bs[128][64];
  const int tid = threadIdx.x;
  const int w = tid >> 6, l = tid & 63;
  const int nwg = gridDim.x, cpx = nwg >> 3, bid = blockIdx.x;
  const int wg = (bid & 7) * cpx + (bid >> 3);
  const int ntN = N_DIM / 128;
  const int m0 = (wg / ntN) * 128, n0 = (wg % ntN) * 128;
  const int wm = w >> 1, wn = w & 1;
  const int lrow = l & 15, lg = l >> 4;
  f32x4 acc[4][4] = {};
  const float s = scale_p[0];
  const int rr = tid >> 1, rh = tid & 1;
  for (int k0 = 0; k0 < K_DIM; k0 += 64) {
    const float* gx = Xf + (size_t)(m0 + rr) * K_DIM + k0 + rh * 32;
    float4 xa[8];
#pragma unroll
    for (int u = 0; u < 8; ++u) xa[u] = ((const float4*)gx)[u];
    bf16* dst = &As[rr][rh * 32];
#pragma unroll
    for (int u = 0; u < 4; ++u) {
      const float4 p = xa[2 * u], q = xa[2 * u + 1];
      bf16x8 o;
      o[0] = (bf16)p.x; o[1] = (bf16)p.y; o[2] = (bf16)p.z; o[3] = (bf16)p.w;
      o[4] = (bf16)q.x; o[5] = (bf16)q.y; o[6] = (bf16)q.z; o[7] = (bf16)q.w;
      *(bf16x8*)(dst + u * 8) = o;
    }
    const int4* gq = (const int4*)(WQ + (size_t)(n0 + rr) * KB + (k0 >> 1) + rh * 16);
    const int4 q0 = gq[0], q1 = gq[1], q2 = gq[2], q3 = gq[3];
    const int vals[16] = {q0.x, q0.y, q0.z, q0.w, q1.x, q1.y, q1.z, q1.w,
                          q2.x, q2.y, q2.z, q2.w, q3.x, q3.y, q3.z, q3.w};
    bf16* bdst = &Bs[rr][rh * 32];
#pragma unroll
    for (int u = 0; u < 4; ++u) {
      bf16x8 ov;
#pragma unroll
      for (int e = 0; e < 4; ++e) {
        const int b = vals[u * 4 + e];
        ov[e * 2]     = (bf16)(dq_hi_f(b) * s);
        ov[e * 2 + 1] = (bf16)(dq_lo_f(b) * s);
      }
      *(bf16x8*)(bdst + u * 8) = ov;
    }
    __syncthreads();
#pragma unroll
    for (int kk = 0; kk < 64; kk += 32) {
      bf16x8 af[4], bfr[4];
#pragma unroll
      for (int i = 0; i < 4; ++i)
        af[i] = *(const bf16x8*)&As[wm * 64 + i * 16 + lrow][kk + lg * 8];
#pragma unroll
      for (int j = 0; j < 4; ++j)
        bfr[j] = *(const bf16x8*)&Bs[wn * 64 + j * 16 + lrow][kk + lg * 8];
#pragma unroll
      for (int i = 0; i < 4; ++i)
#pragma unroll
        for (int j = 0; j < 4; ++j)
          acc[i][j] = __builtin_amdgcn_mfma_f32_16x16x32_bf16(af[i], bfr[j],
                                                              acc[i][j], 0, 0, 0);
    }
    __syncthreads();
  }
  float bv[4];
#pragma unroll
  for (int j = 0; j < 4; ++j) bv[j] = bias[n0 + wn * 64 + j * 16 + lrow];
#pragma unroll
  for (int i = 0; i < 4; ++i)
#pragma unroll
    for (int r = 0; r < 4; ++r) {
      float* orow = out + (size_t)(m0 + wm * 64 + i * 16 + lg * 4 + r) * N_DIM
                        + (n0 + wn * 64 + lrow);
#pragma unroll
      for (int j = 0; j < 4; ++j) orow[j * 16] = acc[i][j][r] + bv[j];
    }
}

extern "C" void kernel_launch(void* const* d_in, const int* in_sizes, int n_in,
                              void* d_out, int out_size, void* d_ws, size_t ws_size,
                              hipStream_t stream) {
  const float* x     = (const float*)d_in[0];
  const int*   wq    = (const int*)d_in[1];
  const float* scale = (const float*)d_in[2];
  const float* bias  = (const float*)d_in[3];
  float*       out   = (float*)d_out;

  const size_t wb = (size_t)N_DIM * K_DIM * sizeof(bf16);   // 33.55 MB
  const size_t xb = (size_t)M_DIM * K_DIM * sizeof(bf16);   // 67.11 MB

  if (ws_size >= wb + xb) {
    bf16* Wd = (bf16*)d_ws;
    bf16* Xc = (bf16*)((char*)d_ws + wb);
    dequant_w<<<(N_DIM * KB / 4) / 256, 256, 0, stream>>>(wq, Wd, scale);
    convert_x<<<((size_t)M_DIM * K_DIM / 8) / 256, 256, 0, stream>>>(x, Xc);
    gemm8p<<<dim3((M_DIM / BM) * (N_DIM / BN)), 512, 0, stream>>>(Xc, Wd, bias, out);
  } else {
    gemm_fused<<<dim3((M_DIM / 128) * (N_DIM / 128)), 256, 0, stream>>>(
        x, wq, scale, bias, out);
  }
}

// Round 5
// 534.287 us; speedup vs baseline: 2.5058x; 2.5058x over previous
//
#include <hip/hip_runtime.h>
#include <hip/hip_bf16.h>
#include <stdint.h>

// INT4Linear: out[m,o] = sum_k x[m,k]*W[o,k]*scale + bias[o]
// M=8192, N=4096, K=4096. x/scale/bias/out fp32 on device; weight int32
// (one sign-extended packed byte). Pipeline:
//   convert_x (fp32->bf16), dequant_w (int4->bf16), gemm8p (256x256x64).
// Round-5 gemm8p: faithful m201 8-phase template. Per 2-K-tile iter:
// 8 phases, each {<=8 ds_read_b128 quadrant | 0-2 half-tile stages | bar |
// lgkm0 | setprio1 16 MFMA setprio0 | bar}; counted vmcnt(4) at ph4/ph8 only.
// Low fragment pressure (<=32 frag VGPRs/phase); launch_bounds(512,1).

typedef __bf16 bf16;
typedef __bf16 bf16x8 __attribute__((ext_vector_type(8)));
typedef float  f32x4  __attribute__((ext_vector_type(4)));

constexpr int M_DIM = 8192;
constexpr int N_DIM = 4096;
constexpr int K_DIM = 4096;
constexpr int KB    = K_DIM / 2;

constexpr int BM = 256;
constexpr int BN = 256;
constexpr int BK = 64;
constexpr int NKT = K_DIM / BK;   // 64 K-tiles

__device__ __forceinline__ void gload_lds16(const void* g, void* l) {
  __builtin_amdgcn_global_load_lds(
      (const __attribute__((address_space(1))) void*)g,
      (__attribute__((address_space(3))) void*)l,
      16, 0, 0);
}

__device__ __forceinline__ void fence_barrier() {
  asm volatile("" ::: "memory");
  __builtin_amdgcn_s_barrier();
  asm volatile("" ::: "memory");
}

__device__ __forceinline__ float dq_hi_f(int b) {
  int sb = (int)(signed char)(b & 0xFF);
  return (float)(sb >> 4);
}
__device__ __forceinline__ float dq_lo_f(int b) {
  int sb = (int)(signed char)(b & 0xFF);
  return (float)(((sb & 15) ^ 8) - 8);
}

// ---------------- x: fp32 -> bf16 ----------------
__global__ void convert_x(const float* __restrict__ x, bf16* __restrict__ xc) {
  const size_t i = (size_t)blockIdx.x * 256 + threadIdx.x;
  const float4 a = ((const float4*)x)[2 * i];
  const float4 b = ((const float4*)x)[2 * i + 1];
  bf16x8 o;
  o[0] = (bf16)a.x; o[1] = (bf16)a.y; o[2] = (bf16)a.z; o[3] = (bf16)a.w;
  o[4] = (bf16)b.x; o[5] = (bf16)b.y; o[6] = (bf16)b.z; o[7] = (bf16)b.w;
  *(bf16x8*)(xc + i * 8) = o;
}

// ---------------- W: packed int4 -> bf16 [N][K] ----------------
__global__ void dequant_w(const int* __restrict__ wq, bf16* __restrict__ W,
                          const float* __restrict__ scale_p) {
  const float s = scale_p[0];
  const size_t idx = (size_t)blockIdx.x * 256 + threadIdx.x;
  const int4 v = ((const int4*)wq)[idx];
  bf16x8 o;
  o[0] = (bf16)(dq_hi_f(v.x) * s); o[1] = (bf16)(dq_lo_f(v.x) * s);
  o[2] = (bf16)(dq_hi_f(v.y) * s); o[3] = (bf16)(dq_lo_f(v.y) * s);
  o[4] = (bf16)(dq_hi_f(v.z) * s); o[5] = (bf16)(dq_lo_f(v.z) * s);
  o[6] = (bf16)(dq_hi_f(v.w) * s); o[7] = (bf16)(dq_lo_f(v.w) * s);
  *(bf16x8*)(W + idx * 8) = o;
}

// ---------------- m201-style 8-phase 256x256 GEMM ----------------
// 512 threads = 8 waves (2M x 4N), per-wave output 128x64 = acc[8][4] f32x4.
// LDS: dbuf A[2][256][64] + B[2][256][64] bf16 = 128 KiB.
// Swizzle involution: col ^= (row&7)<<3; write side via pre-swizzled global
// source (gload_lds dest stays linear), read side via XOR on col.
// Staging region-safety (all stages issued AFTER the barrier that closes the
// phase whose lgkm0 completed the last read of the target region):
//   ph1: A(kt+1) -> buf1.A  (buf1.A last read prev ph8)
//   ph4: B(kt+2) -> buf0.B  (buf0.B last read ph3)
//   ph5: A(kt+2) -> buf0.A  (buf0.A last read ph4)
//   ph8: B(kt+3) -> buf1.B  (buf1.B last read ph7)
// vmcnt(4) at ph4-end: leaves ph4's 4 loads in flight -> A(kt+1) landed (ph5 needs it).
// vmcnt(4) at ph8-end: leaves ph8's 4 loads in flight -> A(kt+2)+B(kt+2) landed
// (next ph1 needs them). Tail iterations degrade to vmcnt(0) (nothing staged after).

#define MMA16(AF, BF, ACCOFF)                                                  \
  {                                                                            \
    _Pragma("unroll") for (int i_ = 0; i_ < 4; ++i_) {                         \
      _Pragma("unroll") for (int j_ = 0; j_ < 4; ++j_) {                       \
        acc[(ACCOFF) + i_][j_] = __builtin_amdgcn_mfma_f32_16x16x32_bf16(      \
            (AF)[i_], (BF)[j_], acc[(ACCOFF) + i_][j_], 0, 0, 0);              \
      }                                                                        \
    }                                                                          \
  }

__global__ void __launch_bounds__(512, 1)
gemm8p(const bf16* __restrict__ Xc, const bf16* __restrict__ W,
       const float* __restrict__ bias, float* __restrict__ out) {
  __shared__ __align__(16) bf16 As[2][BM][BK];
  __shared__ __align__(16) bf16 Bs[2][BN][BK];

  const int tid = threadIdx.x;
  const int w   = tid >> 6;       // wave 0..7
  const int l   = tid & 63;
  const int wm  = w >> 2;         // M half (0..1)
  const int wn  = w & 3;          // N quarter (0..3)
  const int lrow = l & 15, lg = l >> 4;

  // bijective XCD swizzle: 512 wgs, 512%8==0
  const int bid = blockIdx.x;
  const int wg  = (bid & 7) * 64 + (bid >> 3);
  const int m0  = (wg >> 4) * BM;
  const int n0  = (wg & 15) * BN;

  // staging lane geometry (pre-swizzled source; LDS dest linear)
  const int srow = l >> 3;
  const int scol = ((l & 7) ^ srow) << 3;
  const bf16* gA = Xc + (size_t)(m0 + w * 16 + srow) * K_DIM + scol;
  const bf16* gB = W  + (size_t)(n0 + w * 16 + srow) * K_DIM + scol;

  const int rsw = (lrow & 7) << 3;   // read-side col XOR (elements)

  f32x4 acc[8][4] = {};

  // one STAGE_X(KT,H) = one half-tile = 2 gload_lds per thread
#define STAGE_A(KT, H)                                                         \
  {                                                                            \
    gload_lds16(gA + (size_t)((H) * 128) * K_DIM + (KT) * BK,                  \
                &As[(KT) & 1][(H) * 128 + w * 16][0]);                         \
    gload_lds16(gA + (size_t)((H) * 128 + 8) * K_DIM + (KT) * BK,              \
                &As[(KT) & 1][(H) * 128 + w * 16 + 8][0]);                     \
  }
#define STAGE_B(KT, H)                                                         \
  {                                                                            \
    gload_lds16(gB + (size_t)((H) * 128) * K_DIM + (KT) * BK,                  \
                &Bs[(KT) & 1][(H) * 128 + w * 16][0]);                         \
    gload_lds16(gB + (size_t)((H) * 128 + 8) * K_DIM + (KT) * BK,              \
                &Bs[(KT) & 1][(H) * 128 + w * 16 + 8][0]);                     \
  }

  // quadrant reads: 4 x ds_read_b128 each
#define READ_A4(BUF, KS, Q, DST)                                               \
  {                                                                            \
    _Pragma("unroll") for (int i_ = 0; i_ < 4; ++i_)                           \
      DST[i_] = *(const bf16x8*)&As[BUF][wm * 128 + ((Q) * 4 + i_) * 16 + lrow]\
                                       [((KS) * 32 + lg * 8) ^ rsw];           \
  }
#define READ_B4(BUF, KS, DST)                                                  \
  {                                                                            \
    _Pragma("unroll") for (int j_ = 0; j_ < 4; ++j_)                           \
      DST[j_] = *(const bf16x8*)&Bs[BUF][wn * 64 + j_ * 16 + lrow]             \
                                       [((KS) * 32 + lg * 8) ^ rsw];           \
  }

#define LGKM0() asm volatile("s_waitcnt lgkmcnt(0)" ::: "memory")
#define PRIO1() __builtin_amdgcn_s_setprio(1)
#define PRIO0() __builtin_amdgcn_s_setprio(0)

  // ---- prologue: kt0 fully + B(kt1); vmcnt(4) leaves B(kt1) in flight ----
  STAGE_A(0, 0); STAGE_A(0, 1); STAGE_B(0, 0); STAGE_B(0, 1);
  STAGE_B(1, 0); STAGE_B(1, 1);
  asm volatile("s_waitcnt vmcnt(4)" ::: "memory");
  fence_barrier();

  for (int kt = 0; kt < NKT; kt += 2) {
    bf16x8 a[4], b[4];
    // ================= phases 1-4: compute kt (buf0) =================
    // ---- ph1 ----
    STAGE_A(kt + 1, 0); STAGE_A(kt + 1, 1);          // -> buf1.A (free since prev ph8)
    READ_A4(0, 0, 0, a); READ_B4(0, 0, b);
    fence_barrier(); LGKM0();
    PRIO1(); MMA16(a, b, 0); PRIO0();
    fence_barrier();
    // ---- ph2 ----
    {
      bf16x8 a2[4];
      READ_A4(0, 0, 1, a2);
      fence_barrier(); LGKM0();
      PRIO1(); MMA16(a2, b, 4); PRIO0();
      fence_barrier();
    }
    // ---- ph3 ----
    READ_A4(0, 1, 0, a); READ_B4(0, 1, b);
    fence_barrier(); LGKM0();
    PRIO1(); MMA16(a, b, 0); PRIO0();
    fence_barrier();
    // ---- ph4 ----
    {
      bf16x8 a2[4];
      if (kt + 2 < NKT) { STAGE_B(kt + 2, 0); STAGE_B(kt + 2, 1); }  // buf0.B free after ph3
      READ_A4(0, 1, 1, a2);
      fence_barrier(); LGKM0();
      PRIO1(); MMA16(a2, b, 4); PRIO0();
      if (kt + 2 < NKT) { asm volatile("s_waitcnt vmcnt(4)" ::: "memory"); }
      else              { asm volatile("s_waitcnt vmcnt(0)" ::: "memory"); }
      fence_barrier();
    }
    // ================= phases 5-8: compute kt+1 (buf1) =================
    // ---- ph5 ----
    if (kt + 2 < NKT) { STAGE_A(kt + 2, 0); STAGE_A(kt + 2, 1); }    // buf0.A free after ph4
    READ_A4(1, 0, 0, a); READ_B4(1, 0, b);
    fence_barrier(); LGKM0();
    PRIO1(); MMA16(a, b, 0); PRIO0();
    fence_barrier();
    // ---- ph6 ----
    {
      bf16x8 a2[4];
      READ_A4(1, 0, 1, a2);
      fence_barrier(); LGKM0();
      PRIO1(); MMA16(a2, b, 4); PRIO0();
      fence_barrier();
    }
    // ---- ph7 ----
    READ_A4(1, 1, 0, a); READ_B4(1, 1, b);
    fence_barrier(); LGKM0();
    PRIO1(); MMA16(a, b, 0); PRIO0();
    fence_barrier();
    // ---- ph8 ----
    {
      bf16x8 a2[4];
      if (kt + 3 < NKT) { STAGE_B(kt + 3, 0); STAGE_B(kt + 3, 1); }  // buf1.B free after ph7
      READ_A4(1, 1, 1, a2);
      fence_barrier(); LGKM0();
      PRIO1(); MMA16(a2, b, 4); PRIO0();
      if (kt + 3 < NKT) { asm volatile("s_waitcnt vmcnt(4)" ::: "memory"); }
      else              { asm volatile("s_waitcnt vmcnt(0)" ::: "memory"); }
      fence_barrier();
    }
  }

  // ---- epilogue: +bias, fp32 store ----
  float bv[4];
#pragma unroll
  for (int j = 0; j < 4; ++j) bv[j] = bias[n0 + wn * 64 + j * 16 + lrow];

#pragma unroll
  for (int i = 0; i < 8; ++i) {
#pragma unroll
    for (int r = 0; r < 4; ++r) {
      float* orow = out + (size_t)(m0 + wm * 128 + i * 16 + lg * 4 + r) * N_DIM
                        + (n0 + wn * 64 + lrow);
#pragma unroll
      for (int j = 0; j < 4; ++j) orow[j * 16] = acc[i][j][r] + bv[j];
    }
  }
}

// ---------------- fallback (ws too small): fused simple GEMM ----------------
__global__ void __launch_bounds__(256)
gemm_fused(const float* __restrict__ Xf, const int* __restrict__ WQ,
           const float* __restrict__ scale_p, const float* __restrict__ bias,
           float* __restrict__ out) {
  __shared__ __align__(16) bf16 As[128][64];
  __shared__ __align__(16) bf16 Bs[128][64];
  const int tid = threadIdx.x;
  const int w = tid >> 6, l = tid & 63;
  const int nwg = gridDim.x, cpx = nwg >> 3, bid = blockIdx.x;
  const int wg = (bid & 7) * cpx + (bid >> 3);
  const int ntN = N_DIM / 128;
  const int m0 = (wg / ntN) * 128, n0 = (wg % ntN) * 128;
  const int wm = w >> 1, wn = w & 1;
  const int lrow = l & 15, lg = l >> 4;
  f32x4 acc[4][4] = {};
  const float s = scale_p[0];
  const int rr = tid >> 1, rh = tid & 1;
  for (int k0 = 0; k0 < K_DIM; k0 += 64) {
    const float* gx = Xf + (size_t)(m0 + rr) * K_DIM + k0 + rh * 32;
    float4 xa[8];
#pragma unroll
    for (int u = 0; u < 8; ++u) xa[u] = ((const float4*)gx)[u];
    bf16* dst = &As[rr][rh * 32];
#pragma unroll
    for (int u = 0; u < 4; ++u) {
      const float4 p = xa[2 * u], q = xa[2 * u + 1];
      bf16x8 o;
      o[0] = (bf16)p.x; o[1] = (bf16)p.y; o[2] = (bf16)p.z; o[3] = (bf16)p.w;
      o[4] = (bf16)q.x; o[5] = (bf16)q.y; o[6] = (bf16)q.z; o[7] = (bf16)q.w;
      *(bf16x8*)(dst + u * 8) = o;
    }
    const int4* gq = (const int4*)(WQ + (size_t)(n0 + rr) * KB + (k0 >> 1) + rh * 16);
    const int4 q0 = gq[0], q1 = gq[1], q2 = gq[2], q3 = gq[3];
    const int vals[16] = {q0.x, q0.y, q0.z, q0.w, q1.x, q1.y, q1.z, q1.w,
                          q2.x, q2.y, q2.z, q2.w, q3.x, q3.y, q3.z, q3.w};
    bf16* bdst = &Bs[rr][rh * 32];
#pragma unroll
    for (int u = 0; u < 4; ++u) {
      bf16x8 ov;
#pragma unroll
      for (int e = 0; e < 4; ++e) {
        const int b = vals[u * 4 + e];
        ov[e * 2]     = (bf16)(dq_hi_f(b) * s);
        ov[e * 2 + 1] = (bf16)(dq_lo_f(b) * s);
      }
      *(bf16x8*)(bdst + u * 8) = ov;
    }
    __syncthreads();
#pragma unroll
    for (int kk = 0; kk < 64; kk += 32) {
      bf16x8 af[4], bfr[4];
#pragma unroll
      for (int i = 0; i < 4; ++i)
        af[i] = *(const bf16x8*)&As[wm * 64 + i * 16 + lrow][kk + lg * 8];
#pragma unroll
      for (int j = 0; j < 4; ++j)
        bfr[j] = *(const bf16x8*)&Bs[wn * 64 + j * 16 + lrow][kk + lg * 8];
#pragma unroll
      for (int i = 0; i < 4; ++i)
#pragma unroll
        for (int j = 0; j < 4; ++j)
          acc[i][j] = __builtin_amdgcn_mfma_f32_16x16x32_bf16(af[i], bfr[j],
                                                              acc[i][j], 0, 0, 0);
    }
    __syncthreads();
  }
  float bv[4];
#pragma unroll
  for (int j = 0; j < 4; ++j) bv[j] = bias[n0 + wn * 64 + j * 16 + lrow];
#pragma unroll
  for (int i = 0; i < 4; ++i)
#pragma unroll
    for (int r = 0; r < 4; ++r) {
      float* orow = out + (size_t)(m0 + wm * 64 + i * 16 + lg * 4 + r) * N_DIM
                        + (n0 + wn * 64 + lrow);
#pragma unroll
      for (int j = 0; j < 4; ++j) orow[j * 16] = acc[i][j][r] + bv[j];
    }
}

extern "C" void kernel_launch(void* const* d_in, const int* in_sizes, int n_in,
                              void* d_out, int out_size, void* d_ws, size_t ws_size,
                              hipStream_t stream) {
  const float* x     = (const float*)d_in[0];
  const int*   wq    = (const int*)d_in[1];
  const float* scale = (const float*)d_in[2];
  const float* bias  = (const float*)d_in[3];
  float*       out   = (float*)d_out;

  const size_t wb = (size_t)N_DIM * K_DIM * sizeof(bf16);   // 33.55 MB
  const size_t xb = (size_t)M_DIM * K_DIM * sizeof(bf16);   // 67.11 MB

  if (ws_size >= wb + xb) {
    bf16* Wd = (bf16*)d_ws;
    bf16* Xc = (bf16*)((char*)d_ws + wb);
    dequant_w<<<(N_DIM * KB / 4) / 256, 256, 0, stream>>>(wq, Wd, scale);
    convert_x<<<((size_t)M_DIM * K_DIM / 8) / 256, 256, 0, stream>>>(x, Xc);
    gemm8p<<<dim3((M_DIM / BM) * (N_DIM / BN)), 512, 0, stream>>>(Xc, Wd, bias, out);
  } else {
    gemm_fused<<<dim3((M_DIM / 128) * (N_DIM / 128)), 256, 0, stream>>>(
        x, wq, scale, bias, out);
  }
}